// Round 2
// baseline (318.841 us; speedup 1.0000x reference)
//
#include <hip/hip_runtime.h>
#include <hip/hip_bf16.h>

#define LN 96
#define BN 32
#define DM 128
#define EPN 95   // edges per receiver node = L-1

typedef __attribute__((ext_vector_type(8))) short s16x8;
typedef __attribute__((ext_vector_type(4))) float f32x4;

__device__ __forceinline__ float eluf(float x) {
    return x > 0.f ? x : __expf(x) - 1.f;
}

__device__ __forceinline__ unsigned short f2bf(float f) {
    unsigned int u = __float_as_uint(f);
    unsigned int r = (u + 0x7fff + ((u >> 16) & 1)) >> 16;
    return (unsigned short)r;
}

__device__ __forceinline__ float bf2f(unsigned short h) {
    return __uint_as_float(((unsigned int)h) << 16);
}

// ---------------- weight convert: 18 matrices, each dst[m][n][k] = bf16(src_m[k][n]) hi+lo split ----
// order: 0..2 eW2[i]; 3 W0b; 4,5 eW1[0] S/R; 6 nW1[0]; 7 nW2[0]; 8,9 eW1[1] S/R;
//        10 nW1[1]; 11 nW2[1]; 12,13 eW1[2] S/R; 14 nW1[2]; 15 nW2[2]; 16,17 fW1 S/R
struct SrcTab { const float* p[18]; };

__global__ void conv_all_kernel(SrcTab tab, unsigned short* __restrict__ hi,
                                unsigned short* __restrict__ lo) {
    int idx = blockIdx.x * 256 + threadIdx.x;   // < 18*16384 = 294912
    int m = idx >> 14;
    int rem = idx & 16383;
    int n = rem >> 7, k = rem & 127;
    float x = tab.p[m][k * DM + n];
    unsigned short h = f2bf(x);
    hi[idx] = h;
    lo[idx] = f2bf(x - bf2f(h));
}

// ---------------- node stage (MFMA): act=mlp(in); hs=act@WpS; hr=act@WpR+bp ----------------
// 64 rows/block, 4 waves x 16-row tiles, full 128-col width per wave.

__device__ __forceinline__ void mm16(const char* atile, int arow, int l15, int kgrp,
                                     const unsigned short* __restrict__ wh,
                                     const unsigned short* __restrict__ wl,
                                     f32x4 acc[8]) {
    const char* rb = atile + arow * 256;
    const int swz = (arow & 7) << 4;
    s16x8 a[4];
#pragma unroll
    for (int ks = 0; ks < 4; ++ks)
        a[ks] = *(const s16x8*)(rb + (((ks * 32 + kgrp * 8) * 2) ^ swz));
#pragma unroll
    for (int nt = 0; nt < 8; ++nt) {
        const unsigned short* wb = wh + (nt * 16 + l15) * DM + kgrp * 8;
#pragma unroll
        for (int ks = 0; ks < 4; ++ks)
            acc[nt] = __builtin_amdgcn_mfma_f32_16x16x32_bf16(a[ks], *(const s16x8*)(wb + ks * 32), acc[nt], 0, 0, 0);
        const unsigned short* wbl = wl + (nt * 16 + l15) * DM + kgrp * 8;
#pragma unroll
        for (int ks = 0; ks < 4; ++ks)
            acc[nt] = __builtin_amdgcn_mfma_f32_16x16x32_bf16(a[ks], *(const s16x8*)(wbl + ks * 32), acc[nt], 0, 0, 0);
    }
}

__device__ __forceinline__ void store_act_elu(char* atile, int wrow, int l15, int kgrp, f32x4 acc[8]) {
#pragma unroll
    for (int nt = 0; nt < 8; ++nt)
#pragma unroll
        for (int i = 0; i < 4; ++i) {
            int row = wrow + kgrp * 4 + i;        // C/D: col=lane&15, row=(lane>>4)*4+i
            int col = nt * 16 + l15;
            *(unsigned short*)(atile + ((row * 256 + col * 2) ^ ((row & 7) << 4))) = f2bf(eluf(acc[nt][i]));
        }
}

__global__ __launch_bounds__(256) void node_mfma_kernel(
    const float* __restrict__ in,
    const float* __restrict__ W0a, const float* __restrict__ b0a,        // mode0 layer1 (f32)
    const unsigned short* __restrict__ w1h, const unsigned short* __restrict__ w1l,
    const float* __restrict__ b1,                                        // mode1 layer1
    const unsigned short* __restrict__ w2h, const unsigned short* __restrict__ w2l,
    const float* __restrict__ b2,
    const unsigned short* __restrict__ wsh, const unsigned short* __restrict__ wsl,
    const unsigned short* __restrict__ wrh, const unsigned short* __restrict__ wrl,
    const float* __restrict__ bp,
    float* __restrict__ hs, float* __restrict__ hr, int mode) {
    __shared__ char atile[64 * 256];   // 64 rows x 128 bf16, XOR-swizzled
    const int t = threadIdx.x;
    const int row0 = blockIdx.x * 64;
    const int l = t & 63, wid = t >> 6;
    const int l15 = l & 15, kgrp = l >> 4;
    const int wrow = wid * 16;

    // ---- stage activations (or mode0 scalar layer1) into atile ----
    {
        int rr = t >> 2, q = t & 3;
        int swz = (rr & 7) << 4;
        if (mode == 0) {
            int row = row0 + rr;
            int b = row / LN, ll = row - b * LN;
            float4 xin = *(const float4*)(in + (size_t)(ll * BN + b) * 4);
#pragma unroll
            for (int c4 = 0; c4 < 8; ++c4) {
                int c0 = q * 32 + c4 * 4;
                ushort4 pk;
                {
                    float a0 = b0a[c0+0] + xin.x*W0a[c0+0] + xin.y*W0a[DM+c0+0] + xin.z*W0a[2*DM+c0+0] + xin.w*W0a[3*DM+c0+0];
                    float a1 = b0a[c0+1] + xin.x*W0a[c0+1] + xin.y*W0a[DM+c0+1] + xin.z*W0a[2*DM+c0+1] + xin.w*W0a[3*DM+c0+1];
                    float a2 = b0a[c0+2] + xin.x*W0a[c0+2] + xin.y*W0a[DM+c0+2] + xin.z*W0a[2*DM+c0+2] + xin.w*W0a[3*DM+c0+2];
                    float a3 = b0a[c0+3] + xin.x*W0a[c0+3] + xin.y*W0a[DM+c0+3] + xin.z*W0a[2*DM+c0+3] + xin.w*W0a[3*DM+c0+3];
                    pk.x = f2bf(eluf(a0)); pk.y = f2bf(eluf(a1)); pk.z = f2bf(eluf(a2)); pk.w = f2bf(eluf(a3));
                }
                *(ushort4*)(atile + ((rr * 256 + c0 * 2) ^ swz)) = pk;
            }
        } else {
            const float* src = in + (size_t)(row0 + rr) * DM + q * 32;
#pragma unroll
            for (int c4 = 0; c4 < 8; ++c4) {
                float4 f = *(const float4*)(src + c4 * 4);
                ushort4 pk;
                pk.x = f2bf(f.x); pk.y = f2bf(f.y); pk.z = f2bf(f.z); pk.w = f2bf(f.w);
                *(ushort4*)(atile + ((rr * 256 + (q * 32 + c4 * 4) * 2) ^ swz)) = pk;
            }
        }
    }
    __syncthreads();

    f32x4 acc[8];
    // ---- layer1 (mode1 only; mode0's layer1 was the scalar phase above) ----
    if (mode == 1) {
#pragma unroll
        for (int nt = 0; nt < 8; ++nt) { float bb = b1[nt * 16 + l15]; acc[nt] = (f32x4){bb, bb, bb, bb}; }
        mm16(atile, wrow + l15, l15, kgrp, w1h, w1l, acc);
        __syncthreads();
        store_act_elu(atile, wrow, l15, kgrp, acc);
        __syncthreads();
    }
    // ---- layer2 ----
#pragma unroll
    for (int nt = 0; nt < 8; ++nt) { float bb = b2[nt * 16 + l15]; acc[nt] = (f32x4){bb, bb, bb, bb}; }
    mm16(atile, wrow + l15, l15, kgrp, w2h, w2l, acc);
    __syncthreads();
    store_act_elu(atile, wrow, l15, kgrp, acc);
    __syncthreads();
    // ---- projection S (no bias) ----
#pragma unroll
    for (int nt = 0; nt < 8; ++nt) acc[nt] = (f32x4){0.f, 0.f, 0.f, 0.f};
    mm16(atile, wrow + l15, l15, kgrp, wsh, wsl, acc);
#pragma unroll
    for (int nt = 0; nt < 8; ++nt)
#pragma unroll
        for (int i = 0; i < 4; ++i)
            hs[(size_t)(row0 + wrow + kgrp * 4 + i) * DM + nt * 16 + l15] = acc[nt][i];
    // ---- projection R (+bp) ----
#pragma unroll
    for (int nt = 0; nt < 8; ++nt) { float bb = bp[nt * 16 + l15]; acc[nt] = (f32x4){bb, bb, bb, bb}; }
    mm16(atile, wrow + l15, l15, kgrp, wrh, wrl, acc);
#pragma unroll
    for (int nt = 0; nt < 8; ++nt)
#pragma unroll
        for (int i = 0; i < 4; ++i)
            hr[(size_t)(row0 + wrow + kgrp * 4 + i) * DM + nt * 16 + l15] = acc[nt][i];
}

// ---------------- edge kernel: per (b,r): y1=elu(hs[send]+hr[r]); y2=elu(y1@eW2+b2); g[b][r]=mean_rows(y2) ----------------
__global__ __launch_bounds__(256) void edge_kernel(
    const float* __restrict__ hs, const float* __restrict__ hr,
    const unsigned short* __restrict__ w2bt,   // [128][128] bf16, n-major (transposed)
    const float* __restrict__ b2,
    float* __restrict__ g) {
    __shared__ char y1lds[96 * 256];   // 96 rows x 128 bf16, XOR-swizzled
    __shared__ float hrbuf[DM];
    const int r = blockIdx.x, b = blockIdx.y;
    const int t = threadIdx.x;
    const int l = t & 63, w = t >> 6;
    const int n0 = w * 32;
    const int l15 = l & 15, kgrp = l >> 4;

    // B-fragments (held in registers for the whole kernel), from L2-hot weights
    s16x8 bf[2][4];
#pragma unroll
    for (int nt = 0; nt < 2; ++nt)
#pragma unroll
        for (int ks = 0; ks < 4; ++ks)
            bf[nt][ks] = *(const s16x8*)(w2bt + (size_t)(n0 + nt * 16 + l15) * DM + ks * 32 + kgrp * 8);

    if (t < DM) hrbuf[t] = hr[((size_t)b * LN + r) * DM + t];
    __syncthreads();

    // build y1 tile (rows = edges with recv=r; row 95 = zero pad)
    {
        int row = t >> 1;
        int half = (t & 1) * 64;
        if (row < EPN) {
            int j = row + (row >= r);
            const float* src = hs + ((size_t)b * LN + j) * DM + half;
#pragma unroll
            for (int c8 = 0; c8 < 8; ++c8) {
                int c0 = half + c8 * 8;
                float4 f0 = *(const float4*)(src + c8 * 8);
                float4 f1 = *(const float4*)(src + c8 * 8 + 4);
                union { unsigned short us[8]; uint4 v; } pk;
                pk.us[0] = f2bf(eluf(f0.x + hrbuf[c0 + 0]));
                pk.us[1] = f2bf(eluf(f0.y + hrbuf[c0 + 1]));
                pk.us[2] = f2bf(eluf(f0.z + hrbuf[c0 + 2]));
                pk.us[3] = f2bf(eluf(f0.w + hrbuf[c0 + 3]));
                pk.us[4] = f2bf(eluf(f1.x + hrbuf[c0 + 4]));
                pk.us[5] = f2bf(eluf(f1.y + hrbuf[c0 + 5]));
                pk.us[6] = f2bf(eluf(f1.z + hrbuf[c0 + 6]));
                pk.us[7] = f2bf(eluf(f1.w + hrbuf[c0 + 7]));
                *(uint4*)(y1lds + row * 256 + ((c0 * 2) ^ ((row & 7) << 4))) = pk.v;
            }
        } else if (row == EPN) {
#pragma unroll
            for (int c8 = 0; c8 < 8; ++c8) {
                int c0 = half + c8 * 8;
                *(uint4*)(y1lds + row * 256 + ((c0 * 2) ^ ((row & 7) << 4))) = make_uint4(0, 0, 0, 0);
            }
        }
    }
    __syncthreads();

    f32x4 acc[6][2] = {};
#pragma unroll
    for (int mt = 0; mt < 6; ++mt) {
        int arow = mt * 16 + l15;
        const char* rb = y1lds + arow * 256;
        int swz = (arow & 7) << 4;
#pragma unroll
        for (int ks = 0; ks < 4; ++ks) {
            s16x8 a = *(const s16x8*)(rb + (((ks * 32 + kgrp * 8) * 2) ^ swz));
            acc[mt][0] = __builtin_amdgcn_mfma_f32_16x16x32_bf16(a, bf[0][ks], acc[mt][0], 0, 0, 0);
            acc[mt][1] = __builtin_amdgcn_mfma_f32_16x16x32_bf16(a, bf[1][ks], acc[mt][1], 0, 0, 0);
        }
    }

    // epilogue: +b2, elu, column-mean over 95 rows
    float b2c0 = b2[n0 + l15], b2c1 = b2[n0 + 16 + l15];
    float cs0 = 0.f, cs1 = 0.f;
#pragma unroll
    for (int mt = 0; mt < 6; ++mt) {
#pragma unroll
        for (int i = 0; i < 4; ++i) {
            int rowi = mt * 16 + kgrp * 4 + i;   // C/D layout: col=lane&15, row=(lane>>4)*4+i
            if (rowi < EPN) {
                cs0 += eluf(acc[mt][0][i] + b2c0);
                cs1 += eluf(acc[mt][1][i] + b2c1);
            }
        }
    }
    cs0 += __shfl_xor(cs0, 16); cs0 += __shfl_xor(cs0, 32);
    cs1 += __shfl_xor(cs1, 16); cs1 += __shfl_xor(cs1, 32);
    if (l < 16) {
        float* go = g + ((size_t)b * LN + r) * DM + n0;
        go[l] = cs0 * (1.f / 95.f);
        go[16 + l] = cs1 * (1.f / 95.f);
    }
}

// ---------------- final: out[b][e][c] = elu(hs_f[send]+hr_f[recv]) @ fW2 + fb2 ----------------
__global__ void final_kernel(const float* __restrict__ hs, const float* __restrict__ hr,
                             const float* __restrict__ fW2, const float* __restrict__ fb2,
                             float* __restrict__ out) {
    __shared__ float w2l[DM * 6];
    __shared__ float hrbuf[DM];
    const int r = blockIdx.x, b = blockIdx.y;
    const int t = threadIdx.x;   // 128 threads
    hrbuf[t] = hr[((size_t)b * LN + r) * DM + t];
    for (int c = 0; c < 6; ++c) w2l[t * 6 + c] = fW2[t * 6 + c];
    __syncthreads();
    int k = t;
    if (k < EPN) {
        int j = k + (k >= r);
        const float* src = hs + ((size_t)b * LN + j) * DM;
        float acc[6];
        for (int c = 0; c < 6; ++c) acc[c] = fb2[c];
        for (int d0 = 0; d0 < DM; d0 += 4) {
            float4 f = *(const float4*)(src + d0);
            float v0 = eluf(f.x + hrbuf[d0 + 0]);
            float v1 = eluf(f.y + hrbuf[d0 + 1]);
            float v2 = eluf(f.z + hrbuf[d0 + 2]);
            float v3 = eluf(f.w + hrbuf[d0 + 3]);
            for (int c = 0; c < 6; ++c)
                acc[c] += v0 * w2l[(d0 + 0) * 6 + c] + v1 * w2l[(d0 + 1) * 6 + c]
                        + v2 * w2l[(d0 + 2) * 6 + c] + v3 * w2l[(d0 + 3) * 6 + c];
        }
        float* o = out + (((size_t)b * (LN * EPN)) + r * EPN + k) * 6;
        for (int c = 0; c < 6; ++c) o[c] = acc[c];
    }
}

extern "C" void kernel_launch(void* const* d_in, const int* in_sizes, int n_in,
                              void* d_out, int out_size, void* d_ws, size_t ws_size,
                              hipStream_t stream) {
    const float* inputs = (const float*)d_in[0];
    const float* W0a = (const float*)d_in[3];
    const float* b0a = (const float*)d_in[4];
    const float* W0b = (const float*)d_in[5];
    const float* b0b = (const float*)d_in[6];
    const float* eW1 = (const float*)d_in[7];
    const float* eb1 = (const float*)d_in[8];
    const float* eW2 = (const float*)d_in[9];
    const float* eb2 = (const float*)d_in[10];
    const float* nW1 = (const float*)d_in[11];
    const float* nb1 = (const float*)d_in[12];
    const float* nW2 = (const float*)d_in[13];
    const float* nb2 = (const float*)d_in[14];
    const float* fW1 = (const float*)d_in[15];
    const float* fb1 = (const float*)d_in[16];
    const float* fW2 = (const float*)d_in[17];
    const float* fb2 = (const float*)d_in[18];
    float* out = (float*)d_out;

    const int NR = BN * LN;            // 3072 node rows
    float* hs = (float*)d_ws;          // (B,L,128) f32
    float* hr = hs + NR * DM;
    float* g  = hr + NR * DM;
    unsigned short* whi = (unsigned short*)(g + NR * DM);  // 18 x [128][128] bf16 hi
    unsigned short* wlo = whi + 18 * 16384;                // 18 x [128][128] bf16 lo

    SrcTab tab;
    tab.p[0] = eW2;          tab.p[1] = eW2 + 16384;  tab.p[2] = eW2 + 32768;
    tab.p[3] = W0b;
    tab.p[4] = eW1;          tab.p[5] = eW1 + 16384;
    tab.p[6] = nW1;          tab.p[7] = nW2;          tab.p[8] = eW1 + 32768;  tab.p[9]  = eW1 + 49152;
    tab.p[10] = nW1 + 16384; tab.p[11] = nW2 + 16384; tab.p[12] = eW1 + 65536; tab.p[13] = eW1 + 81920;
    tab.p[14] = nW1 + 32768; tab.p[15] = nW2 + 32768; tab.p[16] = fW1;         tab.p[17] = fW1 + 16384;

    dim3 eg(LN, BN);
    #define WM(m) (whi + (m) * 16384), (wlo + (m) * 16384)

    conv_all_kernel<<<1152, 256, 0, stream>>>(tab, whi, wlo);
    // block 0:  mlp0 (scalar W0a layer + W0b) + proj eW1[0]
    node_mfma_kernel<<<48, 256, 0, stream>>>(inputs, W0a, b0a, WM(3), b0b /*unused as b1*/,
                                             WM(3), b0b, WM(4), WM(5), eb1, hs, hr, 0);
    edge_kernel<<<eg, 256, 0, stream>>>(hs, hr, whi, eb2, g);
    // block 1
    node_mfma_kernel<<<48, 256, 0, stream>>>(g, W0a, b0a, WM(6), nb1, WM(7), nb2,
                                             WM(8), WM(9), eb1 + 128, hs, hr, 1);
    edge_kernel<<<eg, 256, 0, stream>>>(hs, hr, whi + 16384, eb2 + 128, g);
    // block 2
    node_mfma_kernel<<<48, 256, 0, stream>>>(g, W0a, b0a, WM(10), nb1 + 128, WM(11), nb2 + 128,
                                             WM(12), WM(13), eb1 + 256, hs, hr, 1);
    edge_kernel<<<eg, 256, 0, stream>>>(hs, hr, whi + 32768, eb2 + 256, g);
    // block 3 + final
    node_mfma_kernel<<<48, 256, 0, stream>>>(g, W0a, b0a, WM(14), nb1 + 256, WM(15), nb2 + 256,
                                             WM(16), WM(17), fb1, hs, hr, 1);
    final_kernel<<<eg, 128, 0, stream>>>(hs, hr, fW2, fb2, out);
    #undef WM
}

// Round 3
// 150.119 us; speedup vs baseline: 2.1239x; 2.1239x over previous
//
#include <hip/hip_runtime.h>
#include <hip/hip_bf16.h>

#define LN 96
#define BN 32
#define DM 128
#define EPN 95   // edges per receiver node = L-1

typedef __attribute__((ext_vector_type(8))) short s16x8;
typedef __attribute__((ext_vector_type(4))) float f32x4;

__device__ __forceinline__ float eluf(float x) {
    return x > 0.f ? x : __expf(x) - 1.f;
}

__device__ __forceinline__ unsigned short f2bf(float f) {
    unsigned int u = __float_as_uint(f);
    return (unsigned short)((u + 0x7fff + ((u >> 16) & 1)) >> 16);
}

__device__ __forceinline__ float bf2f(unsigned short h) {
    return __uint_as_float(((unsigned int)h) << 16);
}

// ---------------- weight pack: fragment-order bf16 hi+lo ----------------
// For matrix m (src row-major [k][n], 128x128 f32):
//   chunk c = (nt*4+ks)*64 + lane, elems e=0..7:
//   pk[m][c][e] = bf16( src[(ks*32 + (lane>>4)*8 + e)*128 + nt*16 + (lane&15)] )
// A wave reading frag (nt,ks) does one fully coalesced 1KB load.
// slots: 0..2 eW2[i]; 3 W0b; 4,5 eW1[0] S/R; 6 nW1[0]; 7 nW2[0]; 8,9 eW1[1] S/R;
//        10 nW1[1]; 11 nW2[1]; 12,13 eW1[2] S/R; 14 nW1[2]; 15 nW2[2]; 16,17 fW1 S/R
struct SrcTab { const float* p[18]; };

__global__ void conv_pack_kernel(SrcTab tab, unsigned short* __restrict__ hi,
                                 unsigned short* __restrict__ lo) {
    int tid = blockIdx.x * 256 + threadIdx.x;   // 18*2048 = 36864
    int m = tid >> 11;
    int c = tid & 2047;
    int l = c & 63, f = c >> 6;
    int n  = (f >> 2) * 16 + (l & 15);
    int k0 = (f & 3) * 32 + (l >> 4) * 8;
    const float* s = tab.p[m] + k0 * DM + n;
    union { unsigned short us[8]; uint4 v; } ph, pl;
#pragma unroll
    for (int e = 0; e < 8; ++e) {
        float x = s[e * DM];
        unsigned short h = f2bf(x);
        ph.us[e] = h;
        pl.us[e] = f2bf(x - bf2f(h));
    }
    *(uint4*)(hi + (size_t)tid * 8) = ph.v;
    *(uint4*)(lo + (size_t)tid * 8) = pl.v;
}

// ---------------- wave-level 16x32 matmul step (2 n-tiles per wave, hi+lo) ----------------
__device__ __forceinline__ void mmw(const char* atile, int l,
                                    const unsigned short* __restrict__ whW,
                                    const unsigned short* __restrict__ wlW,
                                    f32x4 acc[2]) {
    const int l15 = l & 15, kgrp = l >> 4;
    s16x8 a[4];
#pragma unroll
    for (int ks = 0; ks < 4; ++ks)
        a[ks] = *(const s16x8*)(atile + ((l15 * 256 + (ks * 32 + kgrp * 8) * 2) ^ ((l15 & 7) << 4)));
#pragma unroll
    for (int ntl = 0; ntl < 2; ++ntl) {
#pragma unroll
        for (int ks = 0; ks < 4; ++ks) {
            s16x8 bh = *(const s16x8*)(whW + (size_t)((ntl * 4 + ks) * 64 + l) * 8);
            acc[ntl] = __builtin_amdgcn_mfma_f32_16x16x32_bf16(a[ks], bh, acc[ntl], 0, 0, 0);
        }
#pragma unroll
        for (int ks = 0; ks < 4; ++ks) {
            s16x8 bl = *(const s16x8*)(wlW + (size_t)((ntl * 4 + ks) * 64 + l) * 8);
            acc[ntl] = __builtin_amdgcn_mfma_f32_16x16x32_bf16(a[ks], bl, acc[ntl], 0, 0, 0);
        }
    }
}

__device__ __forceinline__ void store_act(char* atile, int l, int w, f32x4 acc[2]) {
    const int l15 = l & 15, kgrp = l >> 4;
#pragma unroll
    for (int ntl = 0; ntl < 2; ++ntl)
#pragma unroll
        for (int i = 0; i < 4; ++i) {
            int row = kgrp * 4 + i;              // C/D: col=lane&15, row=(lane>>4)*4+i
            int col = (2 * w + ntl) * 16 + l15;
            *(unsigned short*)(atile + ((row * 256 + col * 2) ^ ((row & 7) << 4))) = f2bf(eluf(acc[ntl][i]));
        }
}

// ---------------- node stage: act=mlp(in); hs=act@WpS; hr=act@WpR+bp ----------------
// 16 rows/block (192 blocks), 4 waves; wave w owns n-cols [w*32, w*32+32).
__global__ __launch_bounds__(256) void node_mfma_kernel(
    const float* __restrict__ in,
    const float* __restrict__ W0a, const float* __restrict__ b0a,
    const unsigned short* __restrict__ w1h, const unsigned short* __restrict__ w1l,
    const float* __restrict__ b1,
    const unsigned short* __restrict__ w2h, const unsigned short* __restrict__ w2l,
    const float* __restrict__ b2,
    const unsigned short* __restrict__ wsh, const unsigned short* __restrict__ wsl,
    const unsigned short* __restrict__ wrh, const unsigned short* __restrict__ wrl,
    const float* __restrict__ bp,
    float* __restrict__ hs, float* __restrict__ hr, int mode) {
    __shared__ char atile[16 * 256];   // 16 rows x 128 bf16, XOR-swizzled
    const int t = threadIdx.x;
    const int row0 = blockIdx.x * 16;
    const int l = t & 63, w = t >> 6;
    const int l15 = l & 15, kgrp = l >> 4;

    // ---- stage input rows (mode0: fused scalar K=4 layer1) ----
    {
        int rr = t >> 4, q = t & 15;
        int c0 = q * 8;
        int swz = (rr & 7) << 4;
        union { unsigned short us[8]; uint4 v; } pk;
        if (mode == 0) {
            int row = row0 + rr;
            int b = row / LN, ll = row - b * LN;
            float4 xin = *(const float4*)(in + (size_t)(ll * BN + b) * 4);
#pragma unroll
            for (int j = 0; j < 8; ++j) {
                int cc = c0 + j;
                float a = b0a[cc] + xin.x * W0a[cc] + xin.y * W0a[DM + cc]
                        + xin.z * W0a[2 * DM + cc] + xin.w * W0a[3 * DM + cc];
                pk.us[j] = f2bf(eluf(a));
            }
        } else {
            const float* src = in + (size_t)(row0 + rr) * DM + c0;
            float4 f0 = *(const float4*)(src);
            float4 f1 = *(const float4*)(src + 4);
            pk.us[0] = f2bf(f0.x); pk.us[1] = f2bf(f0.y); pk.us[2] = f2bf(f0.z); pk.us[3] = f2bf(f0.w);
            pk.us[4] = f2bf(f1.x); pk.us[5] = f2bf(f1.y); pk.us[6] = f2bf(f1.z); pk.us[7] = f2bf(f1.w);
        }
        *(uint4*)(atile + ((rr * 256 + c0 * 2) ^ swz)) = pk.v;
    }
    __syncthreads();

    f32x4 acc[2];
    const int cA = (2 * w) * 16 + l15, cB = (2 * w + 1) * 16 + l15;

    if (mode == 1) {   // layer1 (mode0 did its K=4 layer1 in the staging phase)
        float ba = b1[cA], bb = b1[cB];
        acc[0] = (f32x4){ba, ba, ba, ba};
        acc[1] = (f32x4){bb, bb, bb, bb};
        mmw(atile, l, w1h + w * 4096, w1l + w * 4096, acc);
        __syncthreads();
        store_act(atile, l, w, acc);
        __syncthreads();
    }
    // layer2
    {
        float ba = b2[cA], bb = b2[cB];
        acc[0] = (f32x4){ba, ba, ba, ba};
        acc[1] = (f32x4){bb, bb, bb, bb};
        mmw(atile, l, w2h + w * 4096, w2l + w * 4096, acc);
        __syncthreads();
        store_act(atile, l, w, acc);
        __syncthreads();
    }
    // projection S (no bias)
    acc[0] = (f32x4){0.f, 0.f, 0.f, 0.f};
    acc[1] = (f32x4){0.f, 0.f, 0.f, 0.f};
    mmw(atile, l, wsh + w * 4096, wsl + w * 4096, acc);
#pragma unroll
    for (int ntl = 0; ntl < 2; ++ntl)
#pragma unroll
        for (int i = 0; i < 4; ++i)
            hs[(size_t)(row0 + kgrp * 4 + i) * DM + (2 * w + ntl) * 16 + l15] = acc[ntl][i];
    // projection R (+bp)
    {
        float ba = bp[cA], bb = bp[cB];
        acc[0] = (f32x4){ba, ba, ba, ba};
        acc[1] = (f32x4){bb, bb, bb, bb};
        mmw(atile, l, wrh + w * 4096, wrl + w * 4096, acc);
    }
#pragma unroll
    for (int ntl = 0; ntl < 2; ++ntl)
#pragma unroll
        for (int i = 0; i < 4; ++i)
            hr[(size_t)(row0 + kgrp * 4 + i) * DM + (2 * w + ntl) * 16 + l15] = acc[ntl][i];
}

// ---------------- edge kernel: per (b,r): y1=elu(hs[send]+hr[r]); y2=elu(y1@eW2+b2); g[b][r]=mean_rows(y2) ----
__global__ __launch_bounds__(256) void edge_kernel(
    const float* __restrict__ hs, const float* __restrict__ hr,
    const unsigned short* __restrict__ w2pk,   // fragment-packed bf16 (hi only)
    const float* __restrict__ b2,
    float* __restrict__ g) {
    __shared__ char y1lds[96 * 256];   // 96 rows x 128 bf16, XOR-swizzled
    __shared__ float hrbuf[DM];
    const int r = blockIdx.x, b = blockIdx.y;
    const int t = threadIdx.x;
    const int l = t & 63, w = t >> 6;
    const int n0 = w * 32;
    const int l15 = l & 15, kgrp = l >> 4;

    // B-fragments: coalesced packed loads, held in registers
    s16x8 bf[2][4];
#pragma unroll
    for (int ntl = 0; ntl < 2; ++ntl)
#pragma unroll
        for (int ks = 0; ks < 4; ++ks)
            bf[ntl][ks] = *(const s16x8*)(w2pk + (size_t)w * 4096 + (size_t)((ntl * 4 + ks) * 64 + l) * 8);

    if (t < DM) hrbuf[t] = hr[((size_t)b * LN + r) * DM + t];
    __syncthreads();

    // build y1 tile: 384 tasks of (row, 32-col chunk), all 256 threads busy
    for (int task = t; task < 384; task += 256) {
        int row = task >> 2;
        int c0 = (task & 3) * 32;
        int swz = (row & 7) << 4;
        if (row < EPN) {
            int j = row + (row >= r);
            const float* src = hs + ((size_t)b * LN + j) * DM + c0;
#pragma unroll
            for (int cc = 0; cc < 32; cc += 8) {
                float4 f0 = *(const float4*)(src + cc);
                float4 f1 = *(const float4*)(src + cc + 4);
                union { unsigned short us[8]; uint4 v; } pk;
                pk.us[0] = f2bf(eluf(f0.x + hrbuf[c0 + cc + 0]));
                pk.us[1] = f2bf(eluf(f0.y + hrbuf[c0 + cc + 1]));
                pk.us[2] = f2bf(eluf(f0.z + hrbuf[c0 + cc + 2]));
                pk.us[3] = f2bf(eluf(f0.w + hrbuf[c0 + cc + 3]));
                pk.us[4] = f2bf(eluf(f1.x + hrbuf[c0 + cc + 4]));
                pk.us[5] = f2bf(eluf(f1.y + hrbuf[c0 + cc + 5]));
                pk.us[6] = f2bf(eluf(f1.z + hrbuf[c0 + cc + 6]));
                pk.us[7] = f2bf(eluf(f1.w + hrbuf[c0 + cc + 7]));
                *(uint4*)(y1lds + ((row * 256 + (c0 + cc) * 2) ^ swz)) = pk.v;
            }
        } else {   // row 95: zero pad
#pragma unroll
            for (int cc = 0; cc < 32; cc += 8)
                *(uint4*)(y1lds + ((row * 256 + (c0 + cc) * 2) ^ swz)) = make_uint4(0, 0, 0, 0);
        }
    }
    __syncthreads();

    f32x4 acc[6][2] = {};
#pragma unroll
    for (int mt = 0; mt < 6; ++mt) {
        int arow = mt * 16 + l15;
        const char* rb = y1lds + arow * 256;
        int swz = (arow & 7) << 4;
#pragma unroll
        for (int ks = 0; ks < 4; ++ks) {
            s16x8 a = *(const s16x8*)(rb + (((ks * 32 + kgrp * 8) * 2) ^ swz));
            acc[mt][0] = __builtin_amdgcn_mfma_f32_16x16x32_bf16(a, bf[0][ks], acc[mt][0], 0, 0, 0);
            acc[mt][1] = __builtin_amdgcn_mfma_f32_16x16x32_bf16(a, bf[1][ks], acc[mt][1], 0, 0, 0);
        }
    }

    // epilogue: +b2, elu, column-mean over 95 rows
    float b2c0 = b2[n0 + l15], b2c1 = b2[n0 + 16 + l15];
    float cs0 = 0.f, cs1 = 0.f;
#pragma unroll
    for (int mt = 0; mt < 6; ++mt) {
#pragma unroll
        for (int i = 0; i < 4; ++i) {
            int rowi = mt * 16 + kgrp * 4 + i;
            if (rowi < EPN) {
                cs0 += eluf(acc[mt][0][i] + b2c0);
                cs1 += eluf(acc[mt][1][i] + b2c1);
            }
        }
    }
    cs0 += __shfl_xor(cs0, 16); cs0 += __shfl_xor(cs0, 32);
    cs1 += __shfl_xor(cs1, 16); cs1 += __shfl_xor(cs1, 32);
    if (l < 16) {
        float* go = g + ((size_t)b * LN + r) * DM + n0;
        go[l] = cs0 * (1.f / 95.f);
        go[16 + l] = cs1 * (1.f / 95.f);
    }
}

// ---------------- final: out[b][e][c] = elu(hs_f[send]+hr_f[recv]) @ fW2 + fb2 ----------------
__global__ void final_kernel(const float* __restrict__ hs, const float* __restrict__ hr,
                             const float* __restrict__ fW2, const float* __restrict__ fb2,
                             float* __restrict__ out) {
    __shared__ float w2l[DM * 6];
    __shared__ float hrbuf[DM];
    const int r = blockIdx.x, b = blockIdx.y;
    const int t = threadIdx.x;   // 128 threads
    hrbuf[t] = hr[((size_t)b * LN + r) * DM + t];
    for (int c = 0; c < 6; ++c) w2l[t * 6 + c] = fW2[t * 6 + c];
    __syncthreads();
    int k = t;
    if (k < EPN) {
        int j = k + (k >= r);
        const float* src = hs + ((size_t)b * LN + j) * DM;
        float acc[6];
        for (int c = 0; c < 6; ++c) acc[c] = fb2[c];
        for (int d0 = 0; d0 < DM; d0 += 4) {
            float4 f = *(const float4*)(src + d0);
            float v0 = eluf(f.x + hrbuf[d0 + 0]);
            float v1 = eluf(f.y + hrbuf[d0 + 1]);
            float v2 = eluf(f.z + hrbuf[d0 + 2]);
            float v3 = eluf(f.w + hrbuf[d0 + 3]);
            for (int c = 0; c < 6; ++c)
                acc[c] += v0 * w2l[(d0 + 0) * 6 + c] + v1 * w2l[(d0 + 1) * 6 + c]
                        + v2 * w2l[(d0 + 2) * 6 + c] + v3 * w2l[(d0 + 3) * 6 + c];
        }
        float* o = out + (((size_t)b * (LN * EPN)) + r * EPN + k) * 6;
        for (int c = 0; c < 6; ++c) o[c] = acc[c];
    }
}

extern "C" void kernel_launch(void* const* d_in, const int* in_sizes, int n_in,
                              void* d_out, int out_size, void* d_ws, size_t ws_size,
                              hipStream_t stream) {
    const float* inputs = (const float*)d_in[0];
    const float* W0a = (const float*)d_in[3];
    const float* b0a = (const float*)d_in[4];
    const float* W0b = (const float*)d_in[5];
    const float* b0b = (const float*)d_in[6];
    const float* eW1 = (const float*)d_in[7];
    const float* eb1 = (const float*)d_in[8];
    const float* eW2 = (const float*)d_in[9];
    const float* eb2 = (const float*)d_in[10];
    const float* nW1 = (const float*)d_in[11];
    const float* nb1 = (const float*)d_in[12];
    const float* nW2 = (const float*)d_in[13];
    const float* nb2 = (const float*)d_in[14];
    const float* fW1 = (const float*)d_in[15];
    const float* fb1 = (const float*)d_in[16];
    const float* fW2 = (const float*)d_in[17];
    const float* fb2 = (const float*)d_in[18];
    float* out = (float*)d_out;

    const int NR = BN * LN;            // 3072 node rows
    float* hs = (float*)d_ws;
    float* hr = hs + NR * DM;
    float* g  = hr + NR * DM;
    unsigned short* whi = (unsigned short*)(g + NR * DM);  // 18 x 16384 packed hi
    unsigned short* wlo = whi + 18 * 16384;                // 18 x 16384 packed lo

    SrcTab tab;
    tab.p[0] = eW2;          tab.p[1] = eW2 + 16384;  tab.p[2] = eW2 + 32768;
    tab.p[3] = W0b;
    tab.p[4] = eW1;          tab.p[5] = eW1 + 16384;
    tab.p[6] = nW1;          tab.p[7] = nW2;          tab.p[8] = eW1 + 32768;  tab.p[9]  = eW1 + 49152;
    tab.p[10] = nW1 + 16384; tab.p[11] = nW2 + 16384; tab.p[12] = eW1 + 65536; tab.p[13] = eW1 + 81920;
    tab.p[14] = nW1 + 32768; tab.p[15] = nW2 + 32768; tab.p[16] = fW1;         tab.p[17] = fW1 + 16384;

    dim3 eg(LN, BN);
    #define WM(m) (whi + (m) * 16384), (wlo + (m) * 16384)

    conv_pack_kernel<<<144, 256, 0, stream>>>(tab, whi, wlo);
    // block 0: fused scalar layer0 (W0a) + W0b + proj eW1[0]
    node_mfma_kernel<<<192, 256, 0, stream>>>(inputs, W0a, b0a, WM(3), b0b,
                                              WM(3), b0b, WM(4), WM(5), eb1, hs, hr, 0);
    edge_kernel<<<eg, 256, 0, stream>>>(hs, hr, whi, eb2, g);
    // block 1
    node_mfma_kernel<<<192, 256, 0, stream>>>(g, W0a, b0a, WM(6), nb1, WM(7), nb2,
                                              WM(8), WM(9), eb1 + 128, hs, hr, 1);
    edge_kernel<<<eg, 256, 0, stream>>>(hs, hr, whi + 16384, eb2 + 128, g);
    // block 2
    node_mfma_kernel<<<192, 256, 0, stream>>>(g, W0a, b0a, WM(10), nb1 + 128, WM(11), nb2 + 128,
                                              WM(12), WM(13), eb1 + 256, hs, hr, 1);
    edge_kernel<<<eg, 256, 0, stream>>>(hs, hr, whi + 32768, eb2 + 256, g);
    // block 3 + final
    node_mfma_kernel<<<192, 256, 0, stream>>>(g, W0a, b0a, WM(14), nb1 + 256, WM(15), nb2 + 256,
                                              WM(16), WM(17), fb1, hs, hr, 1);
    final_kernel<<<eg, 128, 0, stream>>>(hs, hr, fW2, fb2, out);
    #undef WM
}